// Round 1
// baseline (958.595 us; speedup 1.0000x reference)
//
#include <hip/hip_runtime.h>

typedef unsigned short u16;
typedef __bf16 bf16x8 __attribute__((ext_vector_type(8)));
typedef float f32x4 __attribute__((ext_vector_type(4)));

__device__ __forceinline__ u16 f2bf(float v) {
    unsigned u = __float_as_uint(v);
    unsigned r = (u + 0x7fffu + ((u >> 16) & 1u)) >> 16;
    return (u16)r;
}
__device__ __forceinline__ float bf2f(u16 u) { return __uint_as_float(((unsigned)u) << 16); }

__device__ __forceinline__ void async_cp16(const u16* g, u16* l) {
    __builtin_amdgcn_global_load_lds((const __attribute__((address_space(1))) unsigned int*)g,
                                     (__attribute__((address_space(3))) unsigned int*)l, 16, 0, 0);
}

__device__ __forceinline__ void store1(float* C, long i, float v) { C[i] = v; }
__device__ __forceinline__ void store1(u16* C, long i, float v) { C[i] = f2bf(v); }

// C(MxNpad) = A(MxK) * B(Npad x K)^T  (+bias[col]), store cols < n_store.
// M % 128 == 0, Npad % 128 == 0, K % 64 == 0. grid = (Npad/128, M/128), block = 256.
template <typename OutT>
__global__ __launch_bounds__(256) void gemm_nt(
    const u16* __restrict__ A, const u16* __restrict__ B,
    OutT* __restrict__ C, const float* __restrict__ bias,
    int K, int ldc, int n_store)
{
    __shared__ u16 As[128 * 32];
    __shared__ u16 Bs[128 * 32];
    const int tid = threadIdx.x;
    const int lane = tid & 63;
    const int wave = tid >> 6;
    const int wm = wave >> 1, wn = wave & 1;
    const long m0 = (long)blockIdx.y * 128;
    const long n0 = (long)blockIdx.x * 128;

    f32x4 acc[4][4] = {};

    const int lrow = tid >> 2;          // 0..63
    const int lk = (tid & 3) << 3;      // 0,8,16,24
    const u16* Ag = A + (m0 + lrow) * (long)K + lk;
    const u16* Bg = B + (n0 + lrow) * (long)K + lk;
    u16* Asl = As + tid * 8;            // linear LDS layout: byte off = tid*16
    u16* Bsl = Bs + tid * 8;
    const long K64 = (long)64 * K;

    for (int k0 = 0; k0 < K; k0 += 32) {
        async_cp16(Ag + k0, Asl);
        async_cp16(Ag + k0 + K64, Asl + 2048);
        async_cp16(Bg + k0, Bsl);
        async_cp16(Bg + k0 + K64, Bsl + 2048);
        __syncthreads();
        bf16x8 af[4], bg[4];
        const int ro = (lane & 15) * 32 + ((lane >> 4) << 3);
#pragma unroll
        for (int i = 0; i < 4; i++) af[i] = *(const bf16x8*)(As + (wm * 64 + i * 16) * 32 + ro);
#pragma unroll
        for (int j = 0; j < 4; j++) bg[j] = *(const bf16x8*)(Bs + (wn * 64 + j * 16) * 32 + ro);
#pragma unroll
        for (int i = 0; i < 4; i++)
#pragma unroll
            for (int j = 0; j < 4; j++)
                acc[i][j] = __builtin_amdgcn_mfma_f32_16x16x32_bf16(af[i], bg[j], acc[i][j], 0, 0, 0);
        __syncthreads();
    }

#pragma unroll
    for (int i = 0; i < 4; i++) {
        const long row = m0 + wm * 64 + i * 16 + ((lane >> 4) << 2);
#pragma unroll
        for (int j = 0; j < 4; j++) {
            const int col = (int)n0 + wn * 64 + j * 16 + (lane & 15);
            if (col < n_store) {
                const float bv = bias ? bias[col] : 0.0f;
#pragma unroll
                for (int r = 0; r < 4; r++)
                    store1(C, (row + r) * (long)ldc + col, acc[i][j][r] + bv);
            }
        }
    }
}

// inputs fp32 (65536x180) -> bf16 padded (65536x192)
__global__ __launch_bounds__(192) void conv_input(const float* __restrict__ in, u16* __restrict__ out)
{
    const long r = blockIdx.x;
    const int k = threadIdx.x;
    out[r * 192 + k] = (k < 180) ? f2bf(in[r * 180 + k]) : (u16)0;
}

// W1 (180x360) -> W1t bf16 (384x192), zero padded
__global__ __launch_bounds__(192) void prep_w1t(const float* __restrict__ W1, u16* __restrict__ W1t)
{
    const int n = blockIdx.x, k = threadIdx.x;
    W1t[n * 192 + k] = (n < 360 && k < 180) ? f2bf(W1[k * 360 + n]) : (u16)0;
}

// W2 (180x180) -> W2t bf16 (256x192), zero padded
__global__ __launch_bounds__(192) void prep_w2t(const float* __restrict__ W2, u16* __restrict__ W2t)
{
    const int n = blockIdx.x, k = threadIdx.x;
    W2t[n * 192 + k] = (n < 180 && k < 180) ? f2bf(W2[k * 180 + n]) : (u16)0;
}

__global__ __launch_bounds__(640) void prep_bias(const float* __restrict__ b1, const float* __restrict__ b2,
                                                 float* __restrict__ b1p, float* __restrict__ b2p)
{
    const int i = threadIdx.x;
    if (i < 384) b1p[i] = (i < 360) ? b1[i] : 0.0f;
    else { const int j = i - 384; b2p[j] = (j < 180) ? b2[j] : 0.0f; }
}

// per-channel sum / sumsq of x (bf16, 65536 x 384). grid=256 blocks x 384 thr (256 rows/block)
__global__ __launch_bounds__(384) void bn_stats(const u16* __restrict__ x, float* __restrict__ accum)
{
    const int ch = threadIdx.x;
    const long base = (long)blockIdx.x * 256 * 384;
    float s = 0.0f, s2 = 0.0f;
    for (int r = 0; r < 256; r++) {
        const float v = bf2f(x[base + (long)r * 384 + ch]);
        s += v; s2 += v * v;
    }
    atomicAdd(&accum[ch], s);
    atomicAdd(&accum[384 + ch], s2);
}

__global__ __launch_bounds__(384) void bn_finalize(const float* __restrict__ accum,
                                                   const float* __restrict__ bn_scale,
                                                   const float* __restrict__ bn_bias,
                                                   float* __restrict__ se, float* __restrict__ be)
{
    const int ch = threadIdx.x;
    const float mean = accum[ch] * (1.0f / 65536.0f);
    const float var = accum[384 + ch] * (1.0f / 65536.0f) - mean * mean;
    const float sc = (ch < 360) ? bn_scale[ch] : 0.0f;
    const float bi = (ch < 360) ? bn_bias[ch] : 0.0f;
    const float inv = rsqrtf(var + 1e-5f);
    se[ch] = sc * inv;
    be[ch] = bi - mean * sc * inv;
}

// windowed gather with shift + BN-normalize: x(bf16 65536x384) -> q,v (N x Dpad bf16)
__global__ __launch_bounds__(256) void gather_qv(
    const u16* __restrict__ x, const float* __restrict__ se, const float* __restrict__ be,
    u16* __restrict__ q, u16* __restrict__ v,
    int g, int log2ws, int log2wc, int D, int Dpad)
{
    const int n = blockIdx.y;
    const int d = blockIdx.x * 256 + threadIdx.x;
    const long oq = (long)n * Dpad + d;
    if (d >= D) { q[oq] = 0; v[oq] = 0; return; }
    const int ws = 1 << log2ws, s = ws >> 1;
    const int cc = d % 60;
    const int pp = d / 60;
    const int dh = pp >> log2ws, dw = pp & (ws - 1);
    const int wcm = (1 << log2wc) - 1;
    const int wi = n & wcm;
    const int hi = (n >> log2wc) & wcm;
    const int b = n >> (2 * log2wc);
    const int row = ((hi << log2ws) + dh + s) & 127;
    const int col = ((wi << log2ws) + dw + s) & 127;
    const int ch = 120 * g + cc;
    const long src = ((long)((b << 7) + row) * 128 + col) * 384 + ch;
    const float xq = bf2f(x[src]);
    const float xv = bf2f(x[src + 60]);
    q[oq] = f2bf(se[ch] * xq + be[ch]);
    v[oq] = f2bf(se[ch + 60] * xv + be[ch + 60]);
}

// bf16 transpose: src (R x Ccols) -> dst (Ccols x R); R,Ccols % 64 == 0
__global__ __launch_bounds__(256) void transpose_bf16(
    const u16* __restrict__ src, u16* __restrict__ dst, int R, int Ccols)
{
    __shared__ u16 t[64][65];
    const int c0 = blockIdx.x * 64, r0 = blockIdx.y * 64;
    const int tc = threadIdx.x & 63;
    const int tr = threadIdx.x >> 6;   // 0..3
#pragma unroll
    for (int i = 0; i < 16; i++) {
        const int r = tr + i * 4;
        t[r][tc] = src[(long)(r0 + r) * Ccols + c0 + tc];
    }
    __syncthreads();
#pragma unroll
    for (int i = 0; i < 16; i++) {
        const int r = tr + i * 4;
        dst[(long)(c0 + r) * R + r0 + tc] = t[tc][r];
    }
}

// row softmax, in-place fp32 + bf16 copy. N = VPT*256, one block per row.
template <int VPT>
__global__ __launch_bounds__(256) void softmax_rows(float* __restrict__ S, u16* __restrict__ Sb)
{
    const int N = VPT * 256;
    const long base = (long)blockIdx.x * N;
    float* p = S + base;
    u16* pb = Sb + base;
    float v[VPT];
    float mx = -3.0e38f;
#pragma unroll
    for (int i = 0; i < VPT; i++) { v[i] = p[i * 256 + threadIdx.x]; mx = fmaxf(mx, v[i]); }
#pragma unroll
    for (int o = 32; o > 0; o >>= 1) mx = fmaxf(mx, __shfl_down(mx, o, 64));
    __shared__ float redm[4];
    if ((threadIdx.x & 63) == 0) redm[threadIdx.x >> 6] = mx;
    __syncthreads();
    mx = fmaxf(fmaxf(redm[0], redm[1]), fmaxf(redm[2], redm[3]));
    float s = 0.0f;
#pragma unroll
    for (int i = 0; i < VPT; i++) { v[i] = __expf(v[i] - mx); s += v[i]; }
#pragma unroll
    for (int o = 32; o > 0; o >>= 1) s += __shfl_down(s, o, 64);
    __shared__ float reds[4];
    if ((threadIdx.x & 63) == 0) reds[threadIdx.x >> 6] = s;
    __syncthreads();
    s = reds[0] + reds[1] + reds[2] + reds[3];
    const float inv = 1.0f / s;
#pragma unroll
    for (int i = 0; i < VPT; i++) {
        const float r = v[i] * inv;
        p[i * 256 + threadIdx.x] = r;
        pb[i * 256 + threadIdx.x] = f2bf(r);
    }
}

// scatter Y (N x Dpad bf16, valid cols < D) back to spatial (65536 x 192), inverse shift
__global__ __launch_bounds__(256) void scatter_y(
    const u16* __restrict__ Y, u16* __restrict__ Ysp,
    int g, int log2ws, int log2wc, int D, int Dpad)
{
    const int n = blockIdx.y;
    const int d = blockIdx.x * 256 + threadIdx.x;
    if (d >= D) return;
    const int ws = 1 << log2ws, s = ws >> 1;
    const int cc = d % 60;
    const int pp = d / 60;
    const int dh = pp >> log2ws, dw = pp & (ws - 1);
    const int wcm = (1 << log2wc) - 1;
    const int wi = n & wcm;
    const int hi = (n >> log2wc) & wcm;
    const int b = n >> (2 * log2wc);
    const int row = ((hi << log2ws) + dh + s) & 127;
    const int col = ((wi << log2ws) + dw + s) & 127;
    Ysp[((long)((b << 7) + row) * 128 + col) * 192 + 60 * g + cc] = Y[(long)n * Dpad + d];
}

extern "C" void kernel_launch(void* const* d_in, const int* in_sizes, int n_in,
                              void* d_out, int out_size, void* d_ws, size_t ws_size,
                              hipStream_t stream)
{
    const float* in_x = (const float*)d_in[0];
    const float* w1  = (const float*)d_in[1];
    const float* b1  = (const float*)d_in[2];
    const float* bns = (const float*)d_in[3];
    const float* bnb = (const float*)d_in[4];
    const float* w2  = (const float*)d_in[5];
    const float* b2  = (const float*)d_in[6];
    float* out = (float*)d_out;

    char* w = (char*)d_ws;
    // region 0: Abuf (25,165,824 B) union atnb (33,554,432 B) -- Abuf dead before first softmax
    u16* Abuf = (u16*)w;
    u16* atnb = (u16*)w;
    size_t off = 33554432;
    u16* x = (u16*)(w + off);    off += 50331648;   // 65536 x 384 bf16
    u16* W1t = (u16*)(w + off);  off += 147456;     // 384 x 192
    u16* W2t = (u16*)(w + off);  off += 98304;      // 256 x 192
    float* b1p = (float*)(w + off);   off += 4096;
    float* b2p = (float*)(w + off);   off += 4096;
    float* accum = (float*)(w + off); off += 4096;
    float* se = (float*)(w + off);    off += 2048;
    float* be = (float*)(w + off);    off += 2048;
    u16* q  = (u16*)(w + off);   off += 8388608;    // max 4096 x 1024
    u16* v  = (u16*)(w + off);   off += 8388608;
    u16* vt = (u16*)(w + off);   off += 8388608;
    u16* Yb = (u16*)(w + off);   off += 8388608;
    u16* Ysp = (u16*)(w + off);  off += 25165824;   // 65536 x 192 bf16

    hipMemsetAsync(accum, 0, 4096, stream);
    hipMemsetAsync(Ysp, 0, 25165824, stream);

    conv_input<<<65536, 192, 0, stream>>>(in_x, Abuf);
    prep_w1t<<<384, 192, 0, stream>>>(w1, W1t);
    prep_w2t<<<256, 192, 0, stream>>>(w2, W2t);
    prep_bias<<<1, 640, 0, stream>>>(b1, b2, b1p, b2p);

    // conv1: x = Abuf @ W1t^T + b1   (65536 x 384, bf16 out)
    gemm_nt<u16><<<dim3(3, 512), 256, 0, stream>>>(Abuf, W1t, x, b1p, 192, 384, 384);
    bn_stats<<<256, 384, 0, stream>>>(x, accum);
    bn_finalize<<<1, 384, 0, stream>>>(accum, bns, bnb, se, be);

    const int  Ns[3]   = {4096, 1024, 256};
    const int  Ds[3]   = {960, 3840, 15360};
    const int  Dps[3]  = {1024, 3840, 15360};
    const int  l2ws[3] = {2, 3, 4};
    const int  l2wc[3] = {5, 4, 3};
    const long atn_off[3] = {11796480L, 28573696L, 29622272L};

    for (int g = 0; g < 3; g++) {
        const int N = Ns[g], D = Ds[g], Dp = Dps[g];
        gather_qv<<<dim3(Dp / 256, N), 256, 0, stream>>>(x, se, be, q, v, g, l2ws[g], l2wc[g], D, Dp);
        transpose_bf16<<<dim3(Dp / 64, N / 64), 256, 0, stream>>>(v, vt, N, Dp);
        float* S = out + atn_off[g];
        // S = q @ q^T  (fp32, straight into d_out attn slot)
        gemm_nt<float><<<dim3(N / 128, N / 128), 256, 0, stream>>>(q, q, S, nullptr, Dp, N, N);
        if (N == 4096)      softmax_rows<16><<<N, 256, 0, stream>>>(S, atnb);
        else if (N == 1024) softmax_rows<4><<<N, 256, 0, stream>>>(S, atnb);
        else                softmax_rows<1><<<N, 256, 0, stream>>>(S, atnb);
        // Y = atn @ v  == atn @ (v^T)^T  (bf16 out, cols < D)
        gemm_nt<u16><<<dim3(Dp / 128, N / 128), 256, 0, stream>>>(atnb, vt, Yb, nullptr, N, Dp, D);
        scatter_y<<<dim3((D + 255) / 256, N), 256, 0, stream>>>(Yb, Ysp, g, l2ws[g], l2wc[g], D, Dp);
    }

    // conv2: out = Ysp @ W2t^T + b2  (store 180 of 256 cols)
    gemm_nt<float><<<dim3(2, 512), 256, 0, stream>>>(Ysp, W2t, out, b2p, 192, 180, 180);
}

// Round 2
// 599.952 us; speedup vs baseline: 1.5978x; 1.5978x over previous
//
#include <hip/hip_runtime.h>

typedef unsigned short u16;
typedef __bf16 bf16x8 __attribute__((ext_vector_type(8)));
typedef float f32x4 __attribute__((ext_vector_type(4)));

__device__ __forceinline__ u16 f2bf(float v) {
    unsigned u = __float_as_uint(v);
    unsigned r = (u + 0x7fffu + ((u >> 16) & 1u)) >> 16;
    return (u16)r;
}
__device__ __forceinline__ float bf2f(u16 u) { return __uint_as_float(((unsigned)u) << 16); }

__device__ __forceinline__ void async_cp16(const u16* g, u16* l) {
    __builtin_amdgcn_global_load_lds((const __attribute__((address_space(1))) unsigned int*)g,
                                     (__attribute__((address_space(3))) unsigned int*)l, 16, 0, 0);
}

__device__ __forceinline__ void store1(float* C, long i, float v) { C[i] = v; }
__device__ __forceinline__ void store1(u16* C, long i, float v) { C[i] = f2bf(v); }

// C(MxNpad) = A(MxK) * B(Npad x K)^T  (+bias[col]), store cols < n_store.
// M % 128 == 0, Npad % 128 == 0, K % 64 == 0. grid = (Npad/128, M/128), block = 256.
template <typename OutT>
__global__ __launch_bounds__(256) void gemm_nt(
    const u16* __restrict__ A, const u16* __restrict__ B,
    OutT* __restrict__ C, const float* __restrict__ bias,
    int K, int ldc, int n_store)
{
    __shared__ u16 As[128 * 32];
    __shared__ u16 Bs[128 * 32];
    const int tid = threadIdx.x;
    const int lane = tid & 63;
    const int wave = tid >> 6;
    const int wm = wave >> 1, wn = wave & 1;
    const long m0 = (long)blockIdx.y * 128;
    const long n0 = (long)blockIdx.x * 128;

    f32x4 acc[4][4] = {};

    const int lrow = tid >> 2;          // 0..63
    const int lk = (tid & 3) << 3;      // 0,8,16,24
    const u16* Ag = A + (m0 + lrow) * (long)K + lk;
    const u16* Bg = B + (n0 + lrow) * (long)K + lk;
    u16* Asl = As + tid * 8;            // linear LDS layout: byte off = tid*16
    u16* Bsl = Bs + tid * 8;
    const long K64 = (long)64 * K;

    for (int k0 = 0; k0 < K; k0 += 32) {
        async_cp16(Ag + k0, Asl);
        async_cp16(Ag + k0 + K64, Asl + 2048);
        async_cp16(Bg + k0, Bsl);
        async_cp16(Bg + k0 + K64, Bsl + 2048);
        __syncthreads();
        bf16x8 af[4], bg[4];
        const int ro = (lane & 15) * 32 + ((lane >> 4) << 3);
#pragma unroll
        for (int i = 0; i < 4; i++) af[i] = *(const bf16x8*)(As + (wm * 64 + i * 16) * 32 + ro);
#pragma unroll
        for (int j = 0; j < 4; j++) bg[j] = *(const bf16x8*)(Bs + (wn * 64 + j * 16) * 32 + ro);
#pragma unroll
        for (int i = 0; i < 4; i++)
#pragma unroll
            for (int j = 0; j < 4; j++)
                acc[i][j] = __builtin_amdgcn_mfma_f32_16x16x32_bf16(af[i], bg[j], acc[i][j], 0, 0, 0);
        __syncthreads();
    }

#pragma unroll
    for (int i = 0; i < 4; i++) {
        const long row = m0 + wm * 64 + i * 16 + ((lane >> 4) << 2);
#pragma unroll
        for (int j = 0; j < 4; j++) {
            const int col = (int)n0 + wn * 64 + j * 16 + (lane & 15);
            if (col < n_store) {
                const float bv = bias ? bias[col] : 0.0f;
#pragma unroll
                for (int r = 0; r < 4; r++)
                    store1(C, (row + r) * (long)ldc + col, acc[i][j][r] + bv);
            }
        }
    }
}

// Split-K variant: P[split][M][Npad] fp32 partials. grid = (Npad/128, M/128, nsplit).
__global__ __launch_bounds__(256) void gemm_nt_splitk(
    const u16* __restrict__ A, const u16* __restrict__ B,
    float* __restrict__ P, int K, int Ksplit)
{
    __shared__ u16 As[128 * 32];
    __shared__ u16 Bs[128 * 32];
    const int tid = threadIdx.x;
    const int lane = tid & 63;
    const int wave = tid >> 6;
    const int wm = wave >> 1, wn = wave & 1;
    const long m0 = (long)blockIdx.y * 128;
    const long n0 = (long)blockIdx.x * 128;
    const int kbeg = blockIdx.z * Ksplit;
    const int Npad = gridDim.x * 128;
    const long M = (long)gridDim.y * 128;

    f32x4 acc[4][4] = {};

    const int lrow = tid >> 2;
    const int lk = (tid & 3) << 3;
    const u16* Ag = A + (m0 + lrow) * (long)K + lk;
    const u16* Bg = B + (n0 + lrow) * (long)K + lk;
    u16* Asl = As + tid * 8;
    u16* Bsl = Bs + tid * 8;
    const long K64 = (long)64 * K;

    for (int k0 = kbeg; k0 < kbeg + Ksplit; k0 += 32) {
        async_cp16(Ag + k0, Asl);
        async_cp16(Ag + k0 + K64, Asl + 2048);
        async_cp16(Bg + k0, Bsl);
        async_cp16(Bg + k0 + K64, Bsl + 2048);
        __syncthreads();
        bf16x8 af[4], bg[4];
        const int ro = (lane & 15) * 32 + ((lane >> 4) << 3);
#pragma unroll
        for (int i = 0; i < 4; i++) af[i] = *(const bf16x8*)(As + (wm * 64 + i * 16) * 32 + ro);
#pragma unroll
        for (int j = 0; j < 4; j++) bg[j] = *(const bf16x8*)(Bs + (wn * 64 + j * 16) * 32 + ro);
#pragma unroll
        for (int i = 0; i < 4; i++)
#pragma unroll
            for (int j = 0; j < 4; j++)
                acc[i][j] = __builtin_amdgcn_mfma_f32_16x16x32_bf16(af[i], bg[j], acc[i][j], 0, 0, 0);
        __syncthreads();
    }

    float* Pz = P + (long)blockIdx.z * M * Npad;
#pragma unroll
    for (int i = 0; i < 4; i++) {
        const long row = m0 + wm * 64 + i * 16 + ((lane >> 4) << 2);
#pragma unroll
        for (int j = 0; j < 4; j++) {
            const int col = (int)n0 + wn * 64 + j * 16 + (lane & 15);
#pragma unroll
            for (int r = 0; r < 4; r++)
                Pz[(row + r) * (long)Npad + col] = acc[i][j][r];
        }
    }
}

// S[i] = sum_s P[s*MN + i]; grid = MN/256.
__global__ __launch_bounds__(256) void reduce_splitk(
    const float* __restrict__ P, float* __restrict__ S, int nsplit, long MN)
{
    const long i = (long)blockIdx.x * 256 + threadIdx.x;
    float s = 0.0f;
    for (int k = 0; k < nsplit; k++) s += P[(long)k * MN + i];
    S[i] = s;
}

// inputs fp32 (65536x180) -> bf16 padded (65536x192)
__global__ __launch_bounds__(192) void conv_input(const float* __restrict__ in, u16* __restrict__ out)
{
    const long r = blockIdx.x;
    const int k = threadIdx.x;
    out[r * 192 + k] = (k < 180) ? f2bf(in[r * 180 + k]) : (u16)0;
}

// W1 (180x360) -> W1t bf16 (384x192), zero padded
__global__ __launch_bounds__(192) void prep_w1t(const float* __restrict__ W1, u16* __restrict__ W1t)
{
    const int n = blockIdx.x, k = threadIdx.x;
    W1t[n * 192 + k] = (n < 360 && k < 180) ? f2bf(W1[k * 360 + n]) : (u16)0;
}

// W2 (180x180) -> W2t bf16 (256x192), zero padded
__global__ __launch_bounds__(192) void prep_w2t(const float* __restrict__ W2, u16* __restrict__ W2t)
{
    const int n = blockIdx.x, k = threadIdx.x;
    W2t[n * 192 + k] = (n < 180 && k < 180) ? f2bf(W2[k * 180 + n]) : (u16)0;
}

__global__ __launch_bounds__(640) void prep_bias(const float* __restrict__ b1, const float* __restrict__ b2,
                                                 float* __restrict__ b1p, float* __restrict__ b2p)
{
    const int i = threadIdx.x;
    if (i < 384) b1p[i] = (i < 360) ? b1[i] : 0.0f;
    else { const int j = i - 384; b2p[j] = (j < 180) ? b2[j] : 0.0f; }
}

// per-channel sum / sumsq of x (bf16, 65536 x 384). grid=256 blocks x 384 thr (256 rows/block)
__global__ __launch_bounds__(384) void bn_stats(const u16* __restrict__ x, float* __restrict__ accum)
{
    const int ch = threadIdx.x;
    const long base = (long)blockIdx.x * 256 * 384;
    float s = 0.0f, s2 = 0.0f;
    for (int r = 0; r < 256; r++) {
        const float v = bf2f(x[base + (long)r * 384 + ch]);
        s += v; s2 += v * v;
    }
    atomicAdd(&accum[ch], s);
    atomicAdd(&accum[384 + ch], s2);
}

__global__ __launch_bounds__(384) void bn_finalize(const float* __restrict__ accum,
                                                   const float* __restrict__ bn_scale,
                                                   const float* __restrict__ bn_bias,
                                                   float* __restrict__ se, float* __restrict__ be)
{
    const int ch = threadIdx.x;
    const float mean = accum[ch] * (1.0f / 65536.0f);
    const float var = accum[384 + ch] * (1.0f / 65536.0f) - mean * mean;
    const float sc = (ch < 360) ? bn_scale[ch] : 0.0f;
    const float bi = (ch < 360) ? bn_bias[ch] : 0.0f;
    const float inv = rsqrtf(var + 1e-5f);
    se[ch] = sc * inv;
    be[ch] = bi - mean * sc * inv;
}

// windowed gather with shift + BN-normalize: x(bf16 65536x384) -> q,v (N x Dpad bf16)
__global__ __launch_bounds__(256) void gather_qv(
    const u16* __restrict__ x, const float* __restrict__ se, const float* __restrict__ be,
    u16* __restrict__ q, u16* __restrict__ v,
    int g, int log2ws, int log2wc, int D, int Dpad)
{
    const int n = blockIdx.y;
    const int d = blockIdx.x * 256 + threadIdx.x;
    const long oq = (long)n * Dpad + d;
    if (d >= D) { q[oq] = 0; v[oq] = 0; return; }
    const int ws = 1 << log2ws, s = ws >> 1;
    const int cc = d % 60;
    const int pp = d / 60;
    const int dh = pp >> log2ws, dw = pp & (ws - 1);
    const int wcm = (1 << log2wc) - 1;
    const int wi = n & wcm;
    const int hi = (n >> log2wc) & wcm;
    const int b = n >> (2 * log2wc);
    const int row = ((hi << log2ws) + dh + s) & 127;
    const int col = ((wi << log2ws) + dw + s) & 127;
    const int ch = 120 * g + cc;
    const long src = ((long)((b << 7) + row) * 128 + col) * 384 + ch;
    const float xq = bf2f(x[src]);
    const float xv = bf2f(x[src + 60]);
    q[oq] = f2bf(se[ch] * xq + be[ch]);
    v[oq] = f2bf(se[ch + 60] * xv + be[ch + 60]);
}

// bf16 transpose: src (R x Ccols) -> dst (Ccols x R); R,Ccols % 64 == 0
__global__ __launch_bounds__(256) void transpose_bf16(
    const u16* __restrict__ src, u16* __restrict__ dst, int R, int Ccols)
{
    __shared__ u16 t[64][65];
    const int c0 = blockIdx.x * 64, r0 = blockIdx.y * 64;
    const int tc = threadIdx.x & 63;
    const int tr = threadIdx.x >> 6;   // 0..3
#pragma unroll
    for (int i = 0; i < 16; i++) {
        const int r = tr + i * 4;
        t[r][tc] = src[(long)(r0 + r) * Ccols + c0 + tc];
    }
    __syncthreads();
#pragma unroll
    for (int i = 0; i < 16; i++) {
        const int r = tr + i * 4;
        dst[(long)(c0 + r) * R + r0 + tc] = t[tc][r];
    }
}

// row softmax, in-place fp32 + bf16 copy. N = VPT*256, one block per row.
template <int VPT>
__global__ __launch_bounds__(256) void softmax_rows(float* __restrict__ S, u16* __restrict__ Sb)
{
    const int N = VPT * 256;
    const long base = (long)blockIdx.x * N;
    float* p = S + base;
    u16* pb = Sb + base;
    float v[VPT];
    float mx = -3.0e38f;
#pragma unroll
    for (int i = 0; i < VPT; i++) { v[i] = p[i * 256 + threadIdx.x]; mx = fmaxf(mx, v[i]); }
#pragma unroll
    for (int o = 32; o > 0; o >>= 1) mx = fmaxf(mx, __shfl_down(mx, o, 64));
    __shared__ float redm[4];
    if ((threadIdx.x & 63) == 0) redm[threadIdx.x >> 6] = mx;
    __syncthreads();
    mx = fmaxf(fmaxf(redm[0], redm[1]), fmaxf(redm[2], redm[3]));
    float s = 0.0f;
#pragma unroll
    for (int i = 0; i < VPT; i++) { v[i] = __expf(v[i] - mx); s += v[i]; }
#pragma unroll
    for (int o = 32; o > 0; o >>= 1) s += __shfl_down(s, o, 64);
    __shared__ float reds[4];
    if ((threadIdx.x & 63) == 0) reds[threadIdx.x >> 6] = s;
    __syncthreads();
    s = reds[0] + reds[1] + reds[2] + reds[3];
    const float inv = 1.0f / s;
#pragma unroll
    for (int i = 0; i < VPT; i++) {
        const float r = v[i] * inv;
        p[i * 256 + threadIdx.x] = r;
        pb[i * 256 + threadIdx.x] = f2bf(r);
    }
}

// scatter Y (N x Dpad bf16, valid cols < D) back to spatial (65536 x 192), inverse shift
__global__ __launch_bounds__(256) void scatter_y(
    const u16* __restrict__ Y, u16* __restrict__ Ysp,
    int g, int log2ws, int log2wc, int D, int Dpad)
{
    const int n = blockIdx.y;
    const int d = blockIdx.x * 256 + threadIdx.x;
    if (d >= D) return;
    const int ws = 1 << log2ws, s = ws >> 1;
    const int cc = d % 60;
    const int pp = d / 60;
    const int dh = pp >> log2ws, dw = pp & (ws - 1);
    const int wcm = (1 << log2wc) - 1;
    const int wi = n & wcm;
    const int hi = (n >> log2wc) & wcm;
    const int b = n >> (2 * log2wc);
    const int row = ((hi << log2ws) + dh + s) & 127;
    const int col = ((wi << log2ws) + dw + s) & 127;
    Ysp[((long)((b << 7) + row) * 128 + col) * 192 + 60 * g + cc] = Y[(long)n * Dpad + d];
}

extern "C" void kernel_launch(void* const* d_in, const int* in_sizes, int n_in,
                              void* d_out, int out_size, void* d_ws, size_t ws_size,
                              hipStream_t stream)
{
    const float* in_x = (const float*)d_in[0];
    const float* w1  = (const float*)d_in[1];
    const float* b1  = (const float*)d_in[2];
    const float* bns = (const float*)d_in[3];
    const float* bnb = (const float*)d_in[4];
    const float* w2  = (const float*)d_in[5];
    const float* b2  = (const float*)d_in[6];
    float* out = (float*)d_out;

    char* w = (char*)d_ws;
    // region 0 (33.5 MB): Abuf (conv1 input) | splitk partials | atnb (bf16 softmax)
    // lifetimes: Abuf dies after conv1; partials live gemm_splitk->reduce (pre-softmax);
    // atnb lives softmax->PV gemm. All disjoint in stream order.
    u16* Abuf = (u16*)w;
    u16* atnb = (u16*)w;
    float* part = (float*)w;
    size_t off = 33554432;
    u16* x = (u16*)(w + off);    off += 50331648;   // 65536 x 384 bf16
    u16* W1t = (u16*)(w + off);  off += 147456;     // 384 x 192
    u16* W2t = (u16*)(w + off);  off += 98304;      // 256 x 192
    float* b1p = (float*)(w + off);   off += 4096;
    float* b2p = (float*)(w + off);   off += 4096;
    float* accum = (float*)(w + off); off += 4096;
    float* se = (float*)(w + off);    off += 2048;
    float* be = (float*)(w + off);    off += 2048;
    u16* q  = (u16*)(w + off);   off += 8388608;    // max 4096 x 1024
    u16* v  = (u16*)(w + off);   off += 8388608;
    u16* vt = (u16*)(w + off);   off += 8388608;
    u16* Yb = (u16*)(w + off);   off += 8388608;
    u16* Ysp = (u16*)(w + off);  off += 25165824;   // 65536 x 192 bf16

    hipMemsetAsync(accum, 0, 4096, stream);
    hipMemsetAsync(Ysp, 0, 25165824, stream);

    conv_input<<<65536, 192, 0, stream>>>(in_x, Abuf);
    prep_w1t<<<384, 192, 0, stream>>>(w1, W1t);
    prep_w2t<<<256, 192, 0, stream>>>(w2, W2t);
    prep_bias<<<1, 640, 0, stream>>>(b1, b2, b1p, b2p);

    // conv1: x = Abuf @ W1t^T + b1   (65536 x 384, bf16 out)
    gemm_nt<u16><<<dim3(3, 512), 256, 0, stream>>>(Abuf, W1t, x, b1p, 192, 384, 384);
    bn_stats<<<256, 384, 0, stream>>>(x, accum);
    bn_finalize<<<1, 384, 0, stream>>>(accum, bns, bnb, se, be);

    const int  Ns[3]   = {4096, 1024, 256};
    const int  Ds[3]   = {960, 3840, 15360};
    const int  Dps[3]  = {1024, 3840, 15360};
    const int  l2ws[3] = {2, 3, 4};
    const int  l2wc[3] = {5, 4, 3};
    const int  nspl[3] = {1, 6, 60};      // K-splits for q@q^T (K = Dp)
    const long atn_off[3] = {11796480L, 28573696L, 29622272L};

    for (int g = 0; g < 3; g++) {
        const int N = Ns[g], D = Ds[g], Dp = Dps[g];
        gather_qv<<<dim3(Dp / 256, N), 256, 0, stream>>>(x, se, be, q, v, g, l2ws[g], l2wc[g], D, Dp);
        transpose_bf16<<<dim3(Dp / 64, N / 64), 256, 0, stream>>>(v, vt, N, Dp);
        float* S = out + atn_off[g];
        // S = q @ q^T  (fp32, into d_out attn slot)
        if (nspl[g] == 1) {
            gemm_nt<float><<<dim3(N / 128, N / 128), 256, 0, stream>>>(q, q, S, nullptr, Dp, N, N);
        } else {
            gemm_nt_splitk<<<dim3(N / 128, N / 128, nspl[g]), 256, 0, stream>>>(
                q, q, part, Dp, Dp / nspl[g]);
            reduce_splitk<<<(long)N * N / 256, 256, 0, stream>>>(part, S, nspl[g], (long)N * N);
        }
        if (N == 4096)      softmax_rows<16><<<N, 256, 0, stream>>>(S, atnb);
        else if (N == 1024) softmax_rows<4><<<N, 256, 0, stream>>>(S, atnb);
        else                softmax_rows<1><<<N, 256, 0, stream>>>(S, atnb);
        // Y = atn @ v  == atn @ (v^T)^T  (bf16 out, cols < D)
        gemm_nt<u16><<<dim3(Dp / 128, N / 128), 256, 0, stream>>>(atnb, vt, Yb, nullptr, N, Dp, D);
        scatter_y<<<dim3((D + 255) / 256, N), 256, 0, stream>>>(Yb, Ysp, g, l2ws[g], l2wc[g], D, Dp);
    }

    // conv2: out = Ysp @ W2t^T + b2  (store 180 of 256 cols)
    gemm_nt<float><<<dim3(2, 512), 256, 0, stream>>>(Ysp, W2t, out, b2p, 192, 180, 180);
}